// Round 5
// baseline (47.974 us; speedup 1.0000x reference)
//
#include <hip/hip_runtime.h>
#include <math.h>

#define BATCH 16
#define TQL   2048
#define TKL   1024
#define DDEC  256
#define DENC  256
#define DATT  128
#define WIN   3

typedef float f32x4 __attribute__((ext_vector_type(4)));

// workspace layout (floats):
//   kq : 48*256  @ 0       (Wq^T-folded keys:  s_j = q . kq + kb)
//   vo : 48*256  @ 12288   (Wo-folded values:  ctx@Wo^T = 32 * sum a_j vo_j)
//   kb : 48      @ 24576
#define WS_KQ 0
#define WS_VO (48*DDEC)
#define WS_KB (2*48*DDEC)

#define NZBLK 4096   // zero-fill blocks; 134217728 B / 4096 = 32768 B per block

// ---------------------------------------------------------------------------
// Kernel 1: blocks 0..47 run the folded-weight precompute (~4 us);
// blocks 48..4143 stream zeros over attn (pure-store, ~7 TB/s, nt stores).
// ---------------------------------------------------------------------------
__global__ __launch_bounds__(256) void pre_and_zero(
    const float* __restrict__ keys, const float* __restrict__ values,
    const float* __restrict__ Wk, const float* __restrict__ bk,
    const float* __restrict__ Wv, const float* __restrict__ bv,
    const float* __restrict__ Wq, const float* __restrict__ bq,
    const float* __restrict__ Wo, const int* __restrict__ pidx,
    float* __restrict__ ws, float* __restrict__ attn)
{
    const int t = threadIdx.x;

    if (blockIdx.x >= 48) {
        const int zb = blockIdx.x - 48;
        f32x4* p = (f32x4*)attn + (size_t)zb * 2048;   // 2048 float4 per block
        const f32x4 z4 = (f32x4)(0.0f);
        #pragma unroll
        for (int i = 0; i < 8; ++i)
            __builtin_nontemporal_store(z4, p + i * 256 + t);
        return;
    }

    const int blk = blockIdx.x;            // 0..47
    const int b = blk / WIN, j = blk % WIN;
    const int prev = pidx[0];
    const int col = prev + j;
    const bool valid = (col >= 0) && (col < TKL);

    __shared__ float ksh[DENC];
    __shared__ float vsh[DENC];
    __shared__ float kwsh[DATT];
    __shared__ float vwsh[DATT];

    {
        size_t base = ((size_t)b * TKL + (valid ? col : 0)) * DENC + t;
        ksh[t] = valid ? keys[base]   : 0.0f;
        vsh[t] = valid ? values[base] : 0.0f;
    }
    __syncthreads();

    if (t < DATT) {
        const float4* wrow = (const float4*)(Wk + (size_t)t * DENC);
        float acc = 0.0f;
        #pragma unroll 8
        for (int k4 = 0; k4 < DENC / 4; ++k4) {
            float4 w = wrow[k4];
            acc += w.x * ksh[k4*4+0] + w.y * ksh[k4*4+1]
                 + w.z * ksh[k4*4+2] + w.w * ksh[k4*4+3];
        }
        kwsh[t] = acc + bk[t];
    } else {
        const int c = t - DATT;
        const float4* wrow = (const float4*)(Wv + (size_t)c * DENC);
        float acc = 0.0f;
        #pragma unroll 8
        for (int k4 = 0; k4 < DENC / 4; ++k4) {
            float4 w = wrow[k4];
            acc += w.x * vsh[k4*4+0] + w.y * vsh[k4*4+1]
                 + w.z * vsh[k4*4+2] + w.w * vsh[k4*4+3];
        }
        vwsh[c] = acc + bv[c];
    }
    __syncthreads();

    float accq = 0.0f, acco = 0.0f;
    const float4* worow = (const float4*)(Wo + (size_t)t * DATT);
    #pragma unroll 4
    for (int c4 = 0; c4 < DATT / 4; ++c4) {
        float4 w = worow[c4];
        acco += w.x * vwsh[c4*4+0] + w.y * vwsh[c4*4+1]
              + w.z * vwsh[c4*4+2] + w.w * vwsh[c4*4+3];
        accq += kwsh[c4*4+0] * Wq[(size_t)(c4*4+0) * DDEC + t]
              + kwsh[c4*4+1] * Wq[(size_t)(c4*4+1) * DDEC + t]
              + kwsh[c4*4+2] * Wq[(size_t)(c4*4+2) * DDEC + t]
              + kwsh[c4*4+3] * Wq[(size_t)(c4*4+3) * DDEC + t];
    }
    ws[WS_KQ + blk * DDEC + t] = accq;
    ws[WS_VO + blk * DDEC + t] = acco;

    if (t < 64) {
        float pb = bq[t] * kwsh[t] + bq[t + 64] * kwsh[t + 64];
        #pragma unroll
        for (int off = 32; off > 0; off >>= 1) pb += __shfl_xor(pb, off, 64);
        if (t == 0) ws[WS_KB + blk] = pb;
    }
}

// ---------------------------------------------------------------------------
// Kernel 2: 1024 blocks x 32 rows. kq/vo/bo/kb staged in LDS once per block.
// Each 16-lane group owns 2 rows; both rows' q loads are issued before the
// LDS staging so ~900cy of HBM latency hides under staging + row-A compute.
// ---------------------------------------------------------------------------
__device__ __forceinline__ float winval(int ww, float w0, float w1, float w2) {
    float v = (ww == 0) ? w0 : ((ww == 1) ? w1 : ((ww == 2) ? w2 : 0.0f));
    return (ww >= 0 && ww < WIN) ? v : 0.0f;
}

__device__ __forceinline__ void process_row(
    int row, int sub, int prev, int f0, int f1,
    const float4 q0, const float4 q1, const float4 q2, const float4 q3,
    const float* kqsh, const float* vosh, const float* bosh, const float* kbsh,
    float* __restrict__ out, float* __restrict__ attn)
{
    const float4* kq4 = (const float4*)kqsh;
    const float4* vo4 = (const float4*)vosh;
    const float4* bo4 = (const float4*)bosh;

    float p0, p1, p2;
    {
        float4 k0, k1, k2;
        k0 = kq4[ 0 + sub]; k1 = kq4[ 64 + sub]; k2 = kq4[128 + sub];
        p0  = q0.x*k0.x + q0.y*k0.y + q0.z*k0.z + q0.w*k0.w;
        p1  = q0.x*k1.x + q0.y*k1.y + q0.z*k1.z + q0.w*k1.w;
        p2  = q0.x*k2.x + q0.y*k2.y + q0.z*k2.z + q0.w*k2.w;
        k0 = kq4[16 + sub]; k1 = kq4[ 80 + sub]; k2 = kq4[144 + sub];
        p0 += q1.x*k0.x + q1.y*k0.y + q1.z*k0.z + q1.w*k0.w;
        p1 += q1.x*k1.x + q1.y*k1.y + q1.z*k1.z + q1.w*k1.w;
        p2 += q1.x*k2.x + q1.y*k2.y + q1.z*k2.z + q1.w*k2.w;
        k0 = kq4[32 + sub]; k1 = kq4[ 96 + sub]; k2 = kq4[160 + sub];
        p0 += q2.x*k0.x + q2.y*k0.y + q2.z*k0.z + q2.w*k0.w;
        p1 += q2.x*k1.x + q2.y*k1.y + q2.z*k1.z + q2.w*k1.w;
        p2 += q2.x*k2.x + q2.y*k2.y + q2.z*k2.z + q2.w*k2.w;
        k0 = kq4[48 + sub]; k1 = kq4[112 + sub]; k2 = kq4[176 + sub];
        p0 += q3.x*k0.x + q3.y*k0.y + q3.z*k0.z + q3.w*k0.w;
        p1 += q3.x*k1.x + q3.y*k1.y + q3.z*k1.z + q3.w*k1.w;
        p2 += q3.x*k2.x + q3.y*k2.y + q3.z*k2.z + q3.w*k2.w;
    }
    #pragma unroll
    for (int off = 8; off > 0; off >>= 1) {
        p0 += __shfl_xor(p0, off, 64);
        p1 += __shfl_xor(p1, off, 64);
        p2 += __shfl_xor(p2, off, 64);
    }

    float s0 = p0 + kbsh[0];
    float s1 = p1 + kbsh[1];
    float s2 = p2 + kbsh[2];

    const bool v0 = (prev + 0 >= 0) && (prev + 0 < TKL);
    const bool v1 = (prev + 1 >= 0) && (prev + 1 < TKL);
    const bool v2 = (prev + 2 >= 0) && (prev + 2 < TKL);
    const float NEG = -3.0e38f;
    if (!v0) s0 = NEG;
    if (!v1) s1 = NEG;
    if (!v2) s2 = NEG;

    const float m  = fmaxf(s0, fmaxf(s1, s2));
    const float e0 = v0 ? __expf(s0 - m) : 0.0f;
    const float e1 = v1 ? __expf(s1 - m) : 0.0f;
    const float e2 = v2 ? __expf(s2 - m) : 0.0f;
    const float inv = 1.0f / (e0 + e1 + e2);
    const float w0 = e0 * inv, w1 = e1 * inv, w2 = e2 * inv;

    const float CTX_SCALE = 32.0f;            // Tk * sqrt(1/Tk) = sqrt(1024)
    const float RSQ2 = 0.70710678118654752f;  // sqrt(0.5)

    float4* orow = (float4*)(out + (size_t)row * DDEC);
    #pragma unroll
    for (int k = 0; k < 4; ++k) {
        const float4 x0 = vo4[k * 16 + sub];
        const float4 x1 = vo4[k * 16 + 64 + sub];
        const float4 x2 = vo4[k * 16 + 128 + sub];
        const float4 bb = bo4[k * 16 + sub];
        const float4 qq = (k == 0) ? q0 : (k == 1) ? q1 : (k == 2) ? q2 : q3;
        float4 o;
        o.x = (CTX_SCALE * (w0*x0.x + w1*x1.x + w2*x2.x) + bb.x + qq.x) * RSQ2;
        o.y = (CTX_SCALE * (w0*x0.y + w1*x1.y + w2*x2.y) + bb.y + qq.y) * RSQ2;
        o.z = (CTX_SCALE * (w0*x0.z + w1*x1.z + w2*x2.z) + bb.z + qq.z) * RSQ2;
        o.w = (CTX_SCALE * (w0*x0.w + w1*x1.w + w2*x2.w) + bb.w + qq.w) * RSQ2;
        orow[k * 16 + sub] = o;
    }

    if (f0 >= 0) {
        float4* arow = (float4*)(attn + (size_t)row * TKL);
        if ((f0 & 15) == sub) {
            const int c0 = f0 * 4;
            float4 pz;
            pz.x = winval(c0 + 0 - prev, w0, w1, w2);
            pz.y = winval(c0 + 1 - prev, w0, w1, w2);
            pz.z = winval(c0 + 2 - prev, w0, w1, w2);
            pz.w = winval(c0 + 3 - prev, w0, w1, w2);
            arow[f0] = pz;
        }
        if (f1 != f0 && (f1 & 15) == sub) {
            const int c0 = f1 * 4;
            float4 pz;
            pz.x = winval(c0 + 0 - prev, w0, w1, w2);
            pz.y = winval(c0 + 1 - prev, w0, w1, w2);
            pz.z = winval(c0 + 2 - prev, w0, w1, w2);
            pz.w = winval(c0 + 3 - prev, w0, w1, w2);
            arow[f1] = pz;
        }
    }
}

__global__ __launch_bounds__(256) void attn_out(
    const float* __restrict__ query, const float* __restrict__ bo,
    const int* __restrict__ pidx, const float* __restrict__ ws,
    float* __restrict__ out, float* __restrict__ attn)
{
    const int t   = threadIdx.x;
    const int G   = t >> 4;              // group 0..15
    const int sub = t & 15;
    const int blk = blockIdx.x;
    const int b   = blk >> 6;            // 64 blocks per batch (32 rows each)
    const int base = b * WIN;
    const int prev = pidx[0];

    const int rowA = blk * 32 + G;
    const int rowB = rowA + 16;

    // ---- issue q loads for BOTH rows before anything else ----
    const float4* qA = (const float4*)query + (size_t)rowA * 64;
    const float4* qB = (const float4*)query + (size_t)rowB * 64;
    const float4 a0 = qA[ 0 + sub], a1 = qA[16 + sub],
                 a2 = qA[32 + sub], a3 = qA[48 + sub];
    const float4 b0 = qB[ 0 + sub], b1 = qB[16 + sub],
                 b2 = qB[32 + sub], b3 = qB[48 + sub];

    // ---- stage per-batch vectors in LDS (hides under q loads) ----
    __shared__ float kqsh[3 * DDEC];
    __shared__ float vosh[3 * DDEC];
    __shared__ float bosh[DDEC];
    __shared__ float kbsh[WIN];
    #pragma unroll
    for (int j = 0; j < 3; ++j) {
        kqsh[j * DDEC + t] = ws[WS_KQ + (base + j) * DDEC + t];
        vosh[j * DDEC + t] = ws[WS_VO + (base + j) * DDEC + t];
    }
    bosh[t] = bo[t];
    if (t < WIN) kbsh[t] = ws[WS_KB + base + t];
    __syncthreads();

    // ---- window float4 indices (uniform) ----
    int lo = prev < 0 ? 0 : prev;
    int hi = prev + (WIN - 1) > TKL - 1 ? TKL - 1 : prev + (WIN - 1);
    int f0 = -1, f1 = -1;
    if (lo <= hi) { f0 = lo >> 2; f1 = hi >> 2; }

    process_row(rowA, sub, prev, f0, f1, a0, a1, a2, a3,
                kqsh, vosh, bosh, kbsh, out, attn);
    process_row(rowB, sub, prev, f0, f1, b0, b1, b2, b3,
                kqsh, vosh, bosh, kbsh, out, attn);
}

extern "C" void kernel_launch(void* const* d_in, const int* in_sizes, int n_in,
                              void* d_out, int out_size, void* d_ws, size_t ws_size,
                              hipStream_t stream)
{
    const float* query  = (const float*)d_in[0];
    const float* keys   = (const float*)d_in[1];
    const float* values = (const float*)d_in[2];
    const float* Wq     = (const float*)d_in[3];
    const float* bq     = (const float*)d_in[4];
    const float* Wk     = (const float*)d_in[5];
    const float* bk     = (const float*)d_in[6];
    const float* Wv     = (const float*)d_in[7];
    const float* bv     = (const float*)d_in[8];
    const float* Wo     = (const float*)d_in[9];
    const float* bo     = (const float*)d_in[10];
    const int*   pidx   = (const int*)d_in[11];

    float* ws   = (float*)d_ws;
    float* out  = (float*)d_out;
    float* attn = out + (size_t)BATCH * TQL * DDEC;

    pre_and_zero<<<48 + NZBLK, 256, 0, stream>>>(keys, values, Wk, bk, Wv, bv,
                                                 Wq, bq, Wo, pidx, ws, attn);
    attn_out<<<BATCH * TQL / 32, 256, 0, stream>>>(query, bo, pidx, ws, out, attn);
}

// Round 6
// 41.262 us; speedup vs baseline: 1.1627x; 1.1627x over previous
//
#include <hip/hip_runtime.h>
#include <math.h>

#define BATCH 16
#define TQL   2048
#define TKL   1024
#define DDEC  256
#define DENC  256
#define DATT  128
#define WIN   3

// workspace layout (floats):
//   kq : 48*256  @ 0       (Wq^T-folded keys:  s_j = q . kq + kb)
//   vo : 48*256  @ 12288   (Wo-folded values:  ctx@Wo^T = 32 * sum a_j vo_j)
//   kb : 48      @ 24576
#define WS_KQ 0
#define WS_VO (48*DDEC)
#define WS_KB (2*48*DDEC)

#define NZBLK 2048   // zero-fill blocks; 134217728 B / 2048 = 65536 B per block

// ---------------------------------------------------------------------------
// Kernel 1: blocks 0..47 run the folded-weight precompute (~4 us);
// blocks 48..2095 stream zeros over attn (pure-store phase, plain stores —
// R3-proven ~7 TB/s; nontemporal stores regressed in R5).
// ---------------------------------------------------------------------------
__global__ __launch_bounds__(256) void pre_and_zero(
    const float* __restrict__ keys, const float* __restrict__ values,
    const float* __restrict__ Wk, const float* __restrict__ bk,
    const float* __restrict__ Wv, const float* __restrict__ bv,
    const float* __restrict__ Wq, const float* __restrict__ bq,
    const float* __restrict__ Wo, const int* __restrict__ pidx,
    float* __restrict__ ws, float* __restrict__ attn)
{
    const int t = threadIdx.x;

    if (blockIdx.x >= 48) {
        const int zb = blockIdx.x - 48;
        float4* p = (float4*)attn + (size_t)zb * 4096;   // 4096 float4 per block
        const float4 z4 = make_float4(0.0f, 0.0f, 0.0f, 0.0f);
        #pragma unroll
        for (int i = 0; i < 16; ++i) p[i * 256 + t] = z4;
        return;
    }

    const int blk = blockIdx.x;            // 0..47
    const int b = blk / WIN, j = blk % WIN;
    const int prev = pidx[0];
    const int col = prev + j;
    const bool valid = (col >= 0) && (col < TKL);

    __shared__ float ksh[DENC];
    __shared__ float vsh[DENC];
    __shared__ float kwsh[DATT];
    __shared__ float vwsh[DATT];

    {
        size_t base = ((size_t)b * TKL + (valid ? col : 0)) * DENC + t;
        ksh[t] = valid ? keys[base]   : 0.0f;
        vsh[t] = valid ? values[base] : 0.0f;
    }
    __syncthreads();

    if (t < DATT) {
        const float4* wrow = (const float4*)(Wk + (size_t)t * DENC);
        float acc = 0.0f;
        #pragma unroll 8
        for (int k4 = 0; k4 < DENC / 4; ++k4) {
            float4 w = wrow[k4];
            acc += w.x * ksh[k4*4+0] + w.y * ksh[k4*4+1]
                 + w.z * ksh[k4*4+2] + w.w * ksh[k4*4+3];
        }
        kwsh[t] = acc + bk[t];
    } else {
        const int c = t - DATT;
        const float4* wrow = (const float4*)(Wv + (size_t)c * DENC);
        float acc = 0.0f;
        #pragma unroll 8
        for (int k4 = 0; k4 < DENC / 4; ++k4) {
            float4 w = wrow[k4];
            acc += w.x * vsh[k4*4+0] + w.y * vsh[k4*4+1]
                 + w.z * vsh[k4*4+2] + w.w * vsh[k4*4+3];
        }
        vwsh[c] = acc + bv[c];
    }
    __syncthreads();

    float accq = 0.0f, acco = 0.0f;
    const float4* worow = (const float4*)(Wo + (size_t)t * DATT);
    #pragma unroll 4
    for (int c4 = 0; c4 < DATT / 4; ++c4) {
        float4 w = worow[c4];
        acco += w.x * vwsh[c4*4+0] + w.y * vwsh[c4*4+1]
              + w.z * vwsh[c4*4+2] + w.w * vwsh[c4*4+3];
        accq += kwsh[c4*4+0] * Wq[(size_t)(c4*4+0) * DDEC + t]
              + kwsh[c4*4+1] * Wq[(size_t)(c4*4+1) * DDEC + t]
              + kwsh[c4*4+2] * Wq[(size_t)(c4*4+2) * DDEC + t]
              + kwsh[c4*4+3] * Wq[(size_t)(c4*4+3) * DDEC + t];
    }
    ws[WS_KQ + blk * DDEC + t] = accq;
    ws[WS_VO + blk * DDEC + t] = acco;

    if (t < 64) {
        float pb = bq[t] * kwsh[t] + bq[t + 64] * kwsh[t + 64];
        #pragma unroll
        for (int off = 32; off > 0; off >>= 1) pb += __shfl_xor(pb, off, 64);
        if (t == 0) ws[WS_KB + blk] = pb;
    }
}

// ---------------------------------------------------------------------------
// Kernel 2: 1024 blocks x 32 rows. kq/vo/bo/kb staged in LDS once per block.
// Each 16-lane group owns 2 rows; both rows' q loads are issued before the
// LDS staging so HBM latency hides under staging + row-A compute.
// ---------------------------------------------------------------------------
__device__ __forceinline__ float winval(int ww, float w0, float w1, float w2) {
    float v = (ww == 0) ? w0 : ((ww == 1) ? w1 : ((ww == 2) ? w2 : 0.0f));
    return (ww >= 0 && ww < WIN) ? v : 0.0f;
}

__device__ __forceinline__ void process_row(
    int row, int sub, int prev, int f0, int f1,
    const float4 q0, const float4 q1, const float4 q2, const float4 q3,
    const float* kqsh, const float* vosh, const float* bosh, const float* kbsh,
    float* __restrict__ out, float* __restrict__ attn)
{
    const float4* kq4 = (const float4*)kqsh;
    const float4* vo4 = (const float4*)vosh;
    const float4* bo4 = (const float4*)bosh;

    float p0, p1, p2;
    {
        float4 k0, k1, k2;
        k0 = kq4[ 0 + sub]; k1 = kq4[ 64 + sub]; k2 = kq4[128 + sub];
        p0  = q0.x*k0.x + q0.y*k0.y + q0.z*k0.z + q0.w*k0.w;
        p1  = q0.x*k1.x + q0.y*k1.y + q0.z*k1.z + q0.w*k1.w;
        p2  = q0.x*k2.x + q0.y*k2.y + q0.z*k2.z + q0.w*k2.w;
        k0 = kq4[16 + sub]; k1 = kq4[ 80 + sub]; k2 = kq4[144 + sub];
        p0 += q1.x*k0.x + q1.y*k0.y + q1.z*k0.z + q1.w*k0.w;
        p1 += q1.x*k1.x + q1.y*k1.y + q1.z*k1.z + q1.w*k1.w;
        p2 += q1.x*k2.x + q1.y*k2.y + q1.z*k2.z + q1.w*k2.w;
        k0 = kq4[32 + sub]; k1 = kq4[ 96 + sub]; k2 = kq4[160 + sub];
        p0 += q2.x*k0.x + q2.y*k0.y + q2.z*k0.z + q2.w*k0.w;
        p1 += q2.x*k1.x + q2.y*k1.y + q2.z*k1.z + q2.w*k1.w;
        p2 += q2.x*k2.x + q2.y*k2.y + q2.z*k2.z + q2.w*k2.w;
        k0 = kq4[48 + sub]; k1 = kq4[112 + sub]; k2 = kq4[176 + sub];
        p0 += q3.x*k0.x + q3.y*k0.y + q3.z*k0.z + q3.w*k0.w;
        p1 += q3.x*k1.x + q3.y*k1.y + q3.z*k1.z + q3.w*k1.w;
        p2 += q3.x*k2.x + q3.y*k2.y + q3.z*k2.z + q3.w*k2.w;
    }
    #pragma unroll
    for (int off = 8; off > 0; off >>= 1) {
        p0 += __shfl_xor(p0, off, 64);
        p1 += __shfl_xor(p1, off, 64);
        p2 += __shfl_xor(p2, off, 64);
    }

    float s0 = p0 + kbsh[0];
    float s1 = p1 + kbsh[1];
    float s2 = p2 + kbsh[2];

    const bool v0 = (prev + 0 >= 0) && (prev + 0 < TKL);
    const bool v1 = (prev + 1 >= 0) && (prev + 1 < TKL);
    const bool v2 = (prev + 2 >= 0) && (prev + 2 < TKL);
    const float NEG = -3.0e38f;
    if (!v0) s0 = NEG;
    if (!v1) s1 = NEG;
    if (!v2) s2 = NEG;

    const float m  = fmaxf(s0, fmaxf(s1, s2));
    const float e0 = v0 ? __expf(s0 - m) : 0.0f;
    const float e1 = v1 ? __expf(s1 - m) : 0.0f;
    const float e2 = v2 ? __expf(s2 - m) : 0.0f;
    const float inv = 1.0f / (e0 + e1 + e2);
    const float w0 = e0 * inv, w1 = e1 * inv, w2 = e2 * inv;

    const float CTX_SCALE = 32.0f;            // Tk * sqrt(1/Tk) = sqrt(1024)
    const float RSQ2 = 0.70710678118654752f;  // sqrt(0.5)

    float4* orow = (float4*)(out + (size_t)row * DDEC);
    #pragma unroll
    for (int k = 0; k < 4; ++k) {
        const float4 x0 = vo4[k * 16 + sub];
        const float4 x1 = vo4[k * 16 + 64 + sub];
        const float4 x2 = vo4[k * 16 + 128 + sub];
        const float4 bb = bo4[k * 16 + sub];
        const float4 qq = (k == 0) ? q0 : (k == 1) ? q1 : (k == 2) ? q2 : q3;
        float4 o;
        o.x = (CTX_SCALE * (w0*x0.x + w1*x1.x + w2*x2.x) + bb.x + qq.x) * RSQ2;
        o.y = (CTX_SCALE * (w0*x0.y + w1*x1.y + w2*x2.y) + bb.y + qq.y) * RSQ2;
        o.z = (CTX_SCALE * (w0*x0.z + w1*x1.z + w2*x2.z) + bb.z + qq.z) * RSQ2;
        o.w = (CTX_SCALE * (w0*x0.w + w1*x1.w + w2*x2.w) + bb.w + qq.w) * RSQ2;
        orow[k * 16 + sub] = o;
    }

    if (f0 >= 0) {
        float4* arow = (float4*)(attn + (size_t)row * TKL);
        if ((f0 & 15) == sub) {
            const int c0 = f0 * 4;
            float4 pz;
            pz.x = winval(c0 + 0 - prev, w0, w1, w2);
            pz.y = winval(c0 + 1 - prev, w0, w1, w2);
            pz.z = winval(c0 + 2 - prev, w0, w1, w2);
            pz.w = winval(c0 + 3 - prev, w0, w1, w2);
            arow[f0] = pz;
        }
        if (f1 != f0 && (f1 & 15) == sub) {
            const int c0 = f1 * 4;
            float4 pz;
            pz.x = winval(c0 + 0 - prev, w0, w1, w2);
            pz.y = winval(c0 + 1 - prev, w0, w1, w2);
            pz.z = winval(c0 + 2 - prev, w0, w1, w2);
            pz.w = winval(c0 + 3 - prev, w0, w1, w2);
            arow[f1] = pz;
        }
    }
}

__global__ __launch_bounds__(256) void attn_out(
    const float* __restrict__ query, const float* __restrict__ bo,
    const int* __restrict__ pidx, const float* __restrict__ ws,
    float* __restrict__ out, float* __restrict__ attn)
{
    const int t   = threadIdx.x;
    const int G   = t >> 4;              // group 0..15
    const int sub = t & 15;
    const int blk = blockIdx.x;
    const int b   = blk >> 6;            // 64 blocks per batch (32 rows each)
    const int base = b * WIN;
    const int prev = pidx[0];

    const int rowA = blk * 32 + G;
    const int rowB = rowA + 16;

    // ---- issue q loads for BOTH rows before anything else ----
    const float4* qA = (const float4*)query + (size_t)rowA * 64;
    const float4* qB = (const float4*)query + (size_t)rowB * 64;
    const float4 a0 = qA[ 0 + sub], a1 = qA[16 + sub],
                 a2 = qA[32 + sub], a3 = qA[48 + sub];
    const float4 b0 = qB[ 0 + sub], b1 = qB[16 + sub],
                 b2 = qB[32 + sub], b3 = qB[48 + sub];

    // ---- stage per-batch vectors in LDS ----
    __shared__ float kqsh[3 * DDEC];
    __shared__ float vosh[3 * DDEC];
    __shared__ float bosh[DDEC];
    __shared__ float kbsh[WIN];
    #pragma unroll
    for (int j = 0; j < 3; ++j) {
        kqsh[j * DDEC + t] = ws[WS_KQ + (base + j) * DDEC + t];
        vosh[j * DDEC + t] = ws[WS_VO + (base + j) * DDEC + t];
    }
    bosh[t] = bo[t];
    if (t < WIN) kbsh[t] = ws[WS_KB + base + t];
    __syncthreads();

    // ---- window float4 indices (uniform) ----
    int lo = prev < 0 ? 0 : prev;
    int hi = prev + (WIN - 1) > TKL - 1 ? TKL - 1 : prev + (WIN - 1);
    int f0 = -1, f1 = -1;
    if (lo <= hi) { f0 = lo >> 2; f1 = hi >> 2; }

    process_row(rowA, sub, prev, f0, f1, a0, a1, a2, a3,
                kqsh, vosh, bosh, kbsh, out, attn);
    process_row(rowB, sub, prev, f0, f1, b0, b1, b2, b3,
                kqsh, vosh, bosh, kbsh, out, attn);
}

extern "C" void kernel_launch(void* const* d_in, const int* in_sizes, int n_in,
                              void* d_out, int out_size, void* d_ws, size_t ws_size,
                              hipStream_t stream)
{
    const float* query  = (const float*)d_in[0];
    const float* keys   = (const float*)d_in[1];
    const float* values = (const float*)d_in[2];
    const float* Wq     = (const float*)d_in[3];
    const float* bq     = (const float*)d_in[4];
    const float* Wk     = (const float*)d_in[5];
    const float* bk     = (const float*)d_in[6];
    const float* Wv     = (const float*)d_in[7];
    const float* bv     = (const float*)d_in[8];
    const float* Wo     = (const float*)d_in[9];
    const float* bo     = (const float*)d_in[10];
    const int*   pidx   = (const int*)d_in[11];

    float* ws   = (float*)d_ws;
    float* out  = (float*)d_out;
    float* attn = out + (size_t)BATCH * TQL * DDEC;

    pre_and_zero<<<48 + NZBLK, 256, 0, stream>>>(keys, values, Wk, bk, Wv, bv,
                                                 Wq, bq, Wo, pidx, ws, attn);
    attn_out<<<BATCH * TQL / 32, 256, 0, stream>>>(query, bo, pidx, ws, out, attn);
}